// Round 11
// baseline (2940.089 us; speedup 1.0000x reference)
//
#include <hip/hip_runtime.h>
#include <math.h>

#define B 4
#define N 32768
#define D 131
#define S 1024
#define RAD2 0.1f      // reference compares d2 <= RADIUS (=0.1) on SQUARED distance
#define G 4            // FPS blocks per batch (sync participants)
#define TPB 1024       // threads per block
#define PPT 8          // points per thread (N/G/TPB)
#define SLICE (N / G)  // 8192 points per block
#define SLOT_STRIDE 8  // u64s per slot (64B padding)
#define NB_TOTAL 128   // total blocks in fused kernel
#define COPY_BLOCKS 112

// ---------------------------------------------------------------------------
// Pack pts = x[:,:,:3] into SoA (px|py|pz) AND packed float4 {x,y,z,0}.
// ---------------------------------------------------------------------------
__global__ void pack_kernel(const float* __restrict__ x, float* __restrict__ ws) {
    int i = blockIdx.x * blockDim.x + threadIdx.x;
    if (i < B * N) {
        const float* __restrict__ s = x + (size_t)i * D;
        float a = s[0], bb = s[1], c = s[2];
        ws[i]             = a;
        ws[B * N + i]     = bb;
        ws[2 * B * N + i] = c;
        float4* w4 = (float4*)(ws + (size_t)3 * B * N);
        w4[i] = make_float4(a, bb, c, 0.0f);
    }
}

// sc0 load: bypasses L1, served by (XCD-local) L2 -- or L3 on L2 miss.
__device__ inline unsigned long long ld_sc0(const unsigned long long* p) {
    unsigned long long v;
    asm volatile("global_load_dwordx2 %0, %1, off sc0\n\t"
                 "s_waitcnt vmcnt(0)"
                 : "=v"(v) : "v"(p) : "memory");
    return v;
}

// ---------------------------------------------------------------------------
// Fused FPS + copy. 128 blocks x 1024 thr.
// FPS blocks: bid<32 && (bid&7)<4  -> batch = bid&7, g = bid>>3. The 4
// participant blocks of a batch share bid%8, i.e. (heuristically) one XCD ->
// one shared L2. Rendezvous rides that L2:
//   writer: plain store (L2-visible fast path) + agent atomic store (L3 truth)
//   poller: 7x sc0 loads (L2) : 1x agent load (L3 fallback) -- correct even
//   if the XCD placement heuristic fails (agent load eventually sees tag;
//   stale L2/write-backs can only expose OLD tags, which the poll ignores).
// Coords staged in LDS (96 KB), lcl[8] in VGPRs (fits 1024-thr 64-VGPR
// budget, no spills). One __syncthreads per step; wave0 does slot store +
// poll + candidate-coord prefetch overlapped with the 2-stage key reduce;
// waves 1..15 spin on an LDS tag.
// Key: [f32 val:32][32767-idx:15][0:6][tag=s+1:11]; equal tags => u64 max =
// (max val, then min idx) = exact reference tie-break.
// Slot double-buffer safety: buf overwritten at s+2 only after the writer's
// s+1 poll succeeded => every consumer finished reading step s.
// ---------------------------------------------------------------------------
__launch_bounds__(TPB)
__global__ void fps_copy_kernel(const float* __restrict__ x,
                                const float* __restrict__ ws,
                                unsigned long long* __restrict__ gslot, // [B][2][G] 64B-strided
                                float* __restrict__ out_idx,
                                int* __restrict__ idx_int,
                                float* __restrict__ out_x) {
    const int bid = blockIdx.x;
    const bool is_fps = (bid < 32) && ((bid & 7) < 4);

    if (!is_fps) {
        // ---- copy branch: 112 blocks stream x -> out_x ----
        int ci = (bid >= 32) ? (16 + (bid - 32))
                             : ((bid >> 3) * 4 + ((bid & 7) - 4));
        const size_t total4 = (size_t)B * N * D / 4;
        const float4* __restrict__ src = (const float4*)x;
        float4* __restrict__ dst = (float4*)out_x;
        for (size_t i = (size_t)ci * TPB + threadIdx.x; i < total4;
             i += (size_t)COPY_BLOCKS * TPB)
            dst[i] = src[i];
        return;
    }

    const int b = bid & 7;                  // batch 0..3
    const int g = bid >> 3;                 // participant 0..3
    const int t = threadIdx.x;
    const int lane = t & 63;
    const int w = t >> 6;                   // wave 0..15

    __shared__ float s_x[SLICE], s_y[SLICE], s_z[SLICE];   // 96 KB coords
    __shared__ unsigned long long s_wk[2][16];             // wave keys (dbuf)
    __shared__ float s_bc[3];                              // bcast centroid
    __shared__ unsigned s_tag;                             // monotone step tag

    const float* __restrict__ px = ws + (size_t)b * N;
    const float* __restrict__ py = ws + (size_t)(B + b) * N;
    const float* __restrict__ pz = ws + (size_t)(2 * B + b) * N;
    const float4* __restrict__ p4 = (const float4*)(ws + (size_t)3 * B * N) + (size_t)b * N;
    unsigned long long* __restrict__ slots = gslot + (size_t)b * 2 * G * SLOT_STRIDE;

    const int base = g * SLICE;
    float lcl[PPT];
    #pragma unroll
    for (int i = 0; i < PPT / 2; ++i) {
        const int l = 2 * t + 2 * TPB * i;          // local index in [0, 8192)
        *(float2*)&s_x[l] = *(const float2*)&px[base + l];
        *(float2*)&s_y[l] = *(const float2*)&py[base + l];
        *(float2*)&s_z[l] = *(const float2*)&pz[base + l];
        lcl[2*i] = INFINITY; lcl[2*i+1] = INFINITY;
    }
    if (t == 0) s_tag = 0;
    __syncthreads();

    float4 cq = p4[0];
    float cx = cq.x, cy = cq.y, cz = cq.z;   // centroid 0 (ref starts at sel=0)

    for (int s = 0; s < S; ++s) {
        float best = -INFINITY;
        int   bidx = 0;
        #pragma unroll
        for (int i = 0; i < PPT / 2; ++i) {
            const int l = 2 * t + 2 * TPB * i;
            float2 vx = *(const float2*)&s_x[l];
            float2 vy = *(const float2*)&s_y[l];
            float2 vz = *(const float2*)&s_z[l];
            {
                float dx = __fsub_rn(cx, vx.x);
                float dy = __fsub_rn(cy, vy.x);
                float dz = __fsub_rn(cz, vz.x);
                float d2 = __fadd_rn(__fadd_rn(__fmul_rn(dx, dx), __fmul_rn(dy, dy)),
                                     __fmul_rn(dz, dz));
                float c = fminf(lcl[2*i], d2);
                lcl[2*i] = c;
                if (c > best) { best = c; bidx = base + l; }   // strict >: smallest p
            }
            {
                float dx = __fsub_rn(cx, vx.y);
                float dy = __fsub_rn(cy, vy.y);
                float dz = __fsub_rn(cz, vz.y);
                float d2 = __fadd_rn(__fadd_rn(__fmul_rn(dx, dx), __fmul_rn(dy, dy)),
                                     __fmul_rn(dz, dz));
                float c = fminf(lcl[2*i+1], d2);
                lcl[2*i+1] = c;
                if (c > best) { best = c; bidx = base + l + 1; }
            }
        }

        // intra-wave butterfly argmax on (value, smallest idx)
        unsigned hi  = __float_as_uint(best);
        unsigned lo2 = (unsigned)(32767 - bidx);
        #define FPS_COMBINE(OHI, OLO) \
            { unsigned _oh = (OHI), _ol = (OLO); \
              if (_oh > hi || (_oh == hi && _ol > lo2)) { hi = _oh; lo2 = _ol; } }
        { unsigned a = (unsigned)__builtin_amdgcn_update_dpp(0, (int)hi, 0xB1, 0xf, 0xf, true);
          unsigned c2 = (unsigned)__builtin_amdgcn_update_dpp(0, (int)lo2, 0xB1, 0xf, 0xf, true);
          FPS_COMBINE(a, c2); }
        { unsigned a = (unsigned)__builtin_amdgcn_update_dpp(0, (int)hi, 0x4E, 0xf, 0xf, true);
          unsigned c2 = (unsigned)__builtin_amdgcn_update_dpp(0, (int)lo2, 0x4E, 0xf, 0xf, true);
          FPS_COMBINE(a, c2); }
        { unsigned a = (unsigned)__builtin_amdgcn_update_dpp(0, (int)hi, 0x141, 0xf, 0xf, true);
          unsigned c2 = (unsigned)__builtin_amdgcn_update_dpp(0, (int)lo2, 0x141, 0xf, 0xf, true);
          FPS_COMBINE(a, c2); }
        { unsigned a = (unsigned)__builtin_amdgcn_update_dpp(0, (int)hi, 0x140, 0xf, 0xf, true);
          unsigned c2 = (unsigned)__builtin_amdgcn_update_dpp(0, (int)lo2, 0x140, 0xf, 0xf, true);
          FPS_COMBINE(a, c2); }
        { unsigned a = (unsigned)__builtin_amdgcn_ds_swizzle((int)hi, 0x401F);
          unsigned c2 = (unsigned)__builtin_amdgcn_ds_swizzle((int)lo2, 0x401F);
          FPS_COMBINE(a, c2); }
        { unsigned a = (unsigned)__shfl_xor((int)hi, 32, 64);
          unsigned c2 = (unsigned)__shfl_xor((int)lo2, 32, 64);
          FPS_COMBINE(a, c2); }
        #undef FPS_COMBINE

        const int buf = s & 1;
        const unsigned tag = (unsigned)(s + 1);
        const unsigned long long mykey = ((unsigned long long)hi << 32) |
                                         ((unsigned long long)lo2 << 17) | tag;
        if (lane == 0) s_wk[buf][w] = mykey;
        __syncthreads();                             // the ONLY barrier per step

        if (w == 0) {
            // block key = max over 16 wave keys: lane reads key lane&15,
            // then 4-stage shuffle reduce
            unsigned long long bk = s_wk[buf][lane & 15];
            #pragma unroll
            for (int off = 1; off < 16; off <<= 1) {
                unsigned long long o = (unsigned long long)__shfl_xor((long long)bk, off, 64);
                if (o > bk) bk = o;
            }
            unsigned long long* wslot = &slots[((size_t)buf * G + g) * SLOT_STRIDE];
            if (lane == 0) {
                // fast path: plain store -> XCD-local L2
                asm volatile("global_store_dwordx2 %0, %1, off"
                             :: "v"(wslot), "v"(bk) : "memory");
                // truth path: agent store -> L3 (correct across XCDs)
                __hip_atomic_store(wslot, bk, __ATOMIC_RELAXED,
                                   __HIP_MEMORY_SCOPE_AGENT);
            }

            // poll 4 slots: lane i watches slot i&3. 7 sc0 (L2) : 1 agent (L3).
            unsigned long long* myslot = &slots[((size_t)buf * G + (lane & 3)) * SLOT_STRIDE];
            unsigned long long kko;
            int it = 0;
            for (;;) {
                kko = (++it & 7) ? ld_sc0(myslot)
                                 : __hip_atomic_load(myslot, __ATOMIC_RELAXED,
                                                     __HIP_MEMORY_SCOPE_AGENT);
                if (!__any((unsigned)(kko & 0x7FFull) != tag)) break;
            }

            // prefetch per-lane candidate coords, OVERLAPPED with key reduce
            const int idxc = 32767 - (int)((kko >> 17) & 0x7FFF);
            const float4 cand = p4[idxc];

            unsigned long long kk = kko;
            #pragma unroll
            for (int off = 1; off < 4; off <<= 1) {
                unsigned long long o = (unsigned long long)__shfl_xor((long long)kk, off, 64);
                if (o > kk) kk = o;
            }
            unsigned long long mask = __ballot(kko == kk);
            int src = (int)(__ffsll((unsigned long long)mask) - 1);
            cx = __shfl(cand.x, src, 64);
            cy = __shfl(cand.y, src, 64);
            cz = __shfl(cand.z, src, 64);

            if (lane == 0) {
                s_bc[0] = cx; s_bc[1] = cy; s_bc[2] = cz;
                __threadfence_block();               // coords visible before tag
                __hip_atomic_store(&s_tag, tag, __ATOMIC_RELAXED,
                                   __HIP_MEMORY_SCOPE_WORKGROUP);
                if (g == 0) {
                    int sel = 32767 - (int)((kk >> 17) & 0x7FFF);
                    out_idx[(size_t)b * S + s] = (float)sel;
                    idx_int[b * S + s] = sel;
                }
            }
        } else {
            // spin on the local LDS tag (no global traffic), then read coords
            while (__hip_atomic_load(&s_tag, __ATOMIC_RELAXED,
                                     __HIP_MEMORY_SCOPE_WORKGROUP) != tag) {}
            __threadfence_block();
            cx = s_bc[0]; cy = s_bc[1]; cz = s_bc[2];
        }
    }
}

// ---------------------------------------------------------------------------
// Ball query counts: one block (256 thr) per (batch, centroid).
// ---------------------------------------------------------------------------
__launch_bounds__(256)
__global__ void ballq_kernel(const float* __restrict__ ws,
                             const int* __restrict__ idx_int,
                             float* __restrict__ out_counts) {
    __shared__ int s_part[4];
    const int b = blockIdx.x >> 10;
    const int j = blockIdx.x & 1023;
    const int t = threadIdx.x;
    const float* __restrict__ px = ws + (size_t)b * N;
    const float* __restrict__ py = ws + (size_t)(B + b) * N;
    const float* __restrict__ pz = ws + (size_t)(2 * B + b) * N;

    const int ci = idx_int[b * S + j];
    const float cx = px[ci], cy = py[ci], cz = pz[ci];

    int cnt = 0;
    #pragma unroll 4
    for (int p = t; p < N; p += 256) {
        float dx = __fsub_rn(cx, px[p]);
        float dy = __fsub_rn(cy, py[p]);
        float dz = __fsub_rn(cz, pz[p]);
        float d2 = __fadd_rn(__fadd_rn(__fmul_rn(dx, dx), __fmul_rn(dy, dy)),
                             __fmul_rn(dz, dz));
        cnt += (d2 <= RAD2) ? 1 : 0;
    }
    #pragma unroll
    for (int off = 1; off < 64; off <<= 1)
        cnt += __shfl_xor(cnt, off, 64);
    if ((t & 63) == 0) s_part[t >> 6] = cnt;
    __syncthreads();
    if (t == 0)
        out_counts[b * S + j] = (float)(s_part[0] + s_part[1] + s_part[2] + s_part[3]);
}

// ---------------------------------------------------------------------------
extern "C" void kernel_launch(void* const* d_in, const int* in_sizes, int n_in,
                              void* d_out, int out_size, void* d_ws, size_t ws_size,
                              hipStream_t stream) {
    const float* x = (const float*)d_in[0];
    float* out = (float*)d_out;
    float* ws = (float*)d_ws;   // px|py|pz (3BN) | float4 pack (4BN) | idx ints | slots
    int* idx_int = (int*)(ws + (size_t)7 * B * N);
    unsigned long long* gslot = (unsigned long long*)(idx_int + B * S);

    float* out_x      = out;                         // B*N*D floats
    float* out_idx    = out + (size_t)B * N * D;     // B*S floats (idx as f32)
    float* out_counts = out_idx + (size_t)B * S;     // B*S floats (counts as f32)

    // zero the padded slot array: B*2*G slots * 64B = 2 KB
    hipMemsetAsync(gslot, 0,
                   (size_t)B * 2 * G * SLOT_STRIDE * sizeof(unsigned long long), stream);

    hipLaunchKernelGGL(pack_kernel, dim3((B * N + 255) / 256), dim3(256), 0, stream, x, ws);
    hipLaunchKernelGGL(fps_copy_kernel, dim3(NB_TOTAL), dim3(TPB), 0, stream,
                       x, ws, gslot, out_idx, idx_int, out_x);
    hipLaunchKernelGGL(ballq_kernel, dim3(B * S), dim3(256), 0, stream, ws, idx_int, out_counts);
}